// Round 1
// baseline (83.045 us; speedup 1.0000x reference)
//
#include <hip/hip_runtime.h>
#include <math.h>

namespace {
constexpr int kB = 2, kC = 3, kOC = 2, kH = 96, kW = 96;
constexpr int kN   = kH * kW;          // 9216
constexpr int kPix = kB * kOC * kN;    // 36864 output elements
constexpr float kEps   = 1e-5f;
constexpr float kScale = 0.57735026918962576f;  // 1/sqrt(3)

// workspace layout (float indices)
constexpr int WS_M   = 0;    // 18 floats: M[b][cp][c]
constexpr int WS_SUM = 24;   // 2 floats: per-oc sum of pre-BN y
constexpr int WS_SQ  = 26;   // 2 floats: per-oc sum of y^2
constexpr int WS_Y   = 32;   // 36864 floats: pre-BN conv output
}

// K1: M[b][cp][c] = sum_n k[b,cp,n] * q[b,c,n]   (18 dot products, len 9216)
__global__ void k1_corr(const float* __restrict__ q, const float* __restrict__ kk,
                        float* __restrict__ ws) {
    const int idx = blockIdx.x;            // 0..17
    const int b   = idx / 9;
    const int cp  = (idx % 9) / 3;
    const int c   = idx % 3;
    const float* kp = kk + (size_t)(b * kC + cp) * kN;
    const float* qp = q  + (size_t)(b * kC + c ) * kN;
    float part = 0.f;
    for (int n = threadIdx.x; n < kN; n += 256)
        part += kp[n] * qp[n];
    __shared__ float red[256];
    red[threadIdx.x] = part;
    __syncthreads();
    for (int s = 128; s > 0; s >>= 1) {
        if (threadIdx.x < s) red[threadIdx.x] += red[threadIdx.x + s];
        __syncthreads();
    }
    if (threadIdx.x == 0) {
        ws[WS_M + idx] = red[0];
        if (idx == 0) {   // zero BN accumulators (ws is poisoned 0xAA)
            ws[WS_SUM + 0] = 0.f; ws[WS_SUM + 1] = 0.f;
            ws[WS_SQ  + 0] = 0.f; ws[WS_SQ  + 1] = 0.f;
        }
    }
}

// K2: agg-on-the-fly + 3x3 conv + bias -> y (ws), plus per-channel sum/sumsq
__global__ void k2_conv(const float* __restrict__ q, const float* __restrict__ cw,
                        const float* __restrict__ cb, float* __restrict__ ws) {
    const int plane = blockIdx.x / 36;            // b*kOC + oc  (0..3)
    const int b   = plane / kOC;
    const int oc  = plane % kOC;
    const int pix = (blockIdx.x % 36) * 256 + threadIdx.x;  // 0..9215
    const int h = pix / kW, w = pix % kW;

    __shared__ float sM[9];         // M[b][cp][c] for this b
    __shared__ float sW[kC * 9];    // conv_w[oc][ic][kh][kw]
    if (threadIdx.x < 9) sM[threadIdx.x] = ws[WS_M + b * 9 + threadIdx.x];
    if (threadIdx.x >= 64 && threadIdx.x < 64 + kC * 9)
        sW[threadIdx.x - 64] = cw[oc * kC * 9 + (threadIdx.x - 64)];
    __syncthreads();

    const float* qb = q + (size_t)b * kC * kN;
    float acc = cb[oc];
    #pragma unroll
    for (int dh = 0; dh < 3; ++dh) {
        const int hh = h + dh - 1;
        if (hh < 0 || hh >= kH) continue;
        #pragma unroll
        for (int dw = 0; dw < 3; ++dw) {
            const int ww = w + dw - 1;
            if (ww < 0 || ww >= kW) continue;
            const int p = hh * kW + ww;
            const float q0 = qb[p];
            const float q1 = qb[kN + p];
            const float q2 = qb[2 * kN + p];
            #pragma unroll
            for (int ic = 0; ic < kC; ++ic) {
                const float a = kScale * (sM[0 * 3 + ic] * q0 +
                                          sM[1 * 3 + ic] * q1 +
                                          sM[2 * 3 + ic] * q2);
                acc += a * sW[ic * 9 + dh * 3 + dw];
            }
        }
    }
    ws[WS_Y + plane * kN + pix] = acc;

    // block reduction of sum / sumsq for BN stats (block is single (b,oc) plane)
    __shared__ float rs[256], rq[256];
    rs[threadIdx.x] = acc;
    rq[threadIdx.x] = acc * acc;
    __syncthreads();
    for (int s = 128; s > 0; s >>= 1) {
        if (threadIdx.x < s) {
            rs[threadIdx.x] += rs[threadIdx.x + s];
            rq[threadIdx.x] += rq[threadIdx.x + s];
        }
        __syncthreads();
    }
    if (threadIdx.x == 0) {
        atomicAdd(&ws[WS_SUM + oc], rs[0]);
        atomicAdd(&ws[WS_SQ  + oc], rq[0]);
    }
}

// K3: batchnorm (training stats, biased var) + gamma/beta + LeakyReLU(0.1)
__global__ void k3_bn(const float* __restrict__ ws, const float* __restrict__ gamma,
                      const float* __restrict__ beta, float* __restrict__ out) {
    const int i  = blockIdx.x * 256 + threadIdx.x;   // 0..36863
    const int oc = (i / kN) % kOC;
    const float inv  = 1.f / (float)(kB * kN);
    const float mean = ws[WS_SUM + oc] * inv;
    const float var  = ws[WS_SQ + oc] * inv - mean * mean;
    const float rstd = rsqrtf(var + kEps);
    float y = (ws[WS_Y + i] - mean) * rstd * gamma[oc] + beta[oc];
    out[i] = (y >= 0.f) ? y : 0.1f * y;
}

extern "C" void kernel_launch(void* const* d_in, const int* in_sizes, int n_in,
                              void* d_out, int out_size, void* d_ws, size_t ws_size,
                              hipStream_t stream) {
    const float* X      = (const float*)d_in[0];  // X_tnext   (2,3,96,96)
    const float* Xhat   = (const float*)d_in[1];  // X_hat_tnext
    const float* conv_w = (const float*)d_in[2];  // (2,3,3,3)
    const float* conv_b = (const float*)d_in[3];  // (2,)
    const float* gamma  = (const float*)d_in[4];  // (2,)
    const float* beta   = (const float*)d_in[5];  // (2,)
    float* out = (float*)d_out;
    float* ws  = (float*)d_ws;

    k1_corr<<<kB * kC * kC, 256, 0, stream>>>(X, Xhat, ws);
    k2_conv<<<kPix / 256, 256, 0, stream>>>(X, conv_w, conv_b, ws);
    k3_bn  <<<kPix / 256, 256, 0, stream>>>(ws, gamma, beta, out);
}